// Round 12
// baseline (236.777 us; speedup 1.0000x reference)
//
#include <hip/hip_runtime.h>
#include <hip/hip_bf16.h>

// GLM flash attention fwd: b=2, s=2048, nh=16, hs=64, fp32 I/O, bf16 MFMA.
// R19 = R18 with the MFMA16 builtin fixed (direct __builtin_amdgcn_mfma_
// f32_16x16x16bf16_1k -- the __has_builtin guard is false in the HOST pass
// and selected a nonexistent fallback name; device builtins parse fine in
// both passes when used directly, as every prior round proved for the
// 16x16x32 builtin). Design unchanged:
// Registers-only softmax -- the P-tile LDS round-trip (128 ds_write_b16 +
// 4 ds_read_b128 + 2 lgkm drains per chunk, the 695K bank-conflict source)
// is eliminated by layout algebra:
//  (1) swapped QK^T: S = MFMA(K_frag, Q_frag) (same frags, swapped operands)
//      -> lane holds P[q=col][k=kg*16+quad*4+r] in the C-layout.
//  (2) that k-pattern IS the A-frag layout of v_mfma_f32_16x16x16_bf16
//      (ISA cdna4 10: 2-VGPR A/B = 4 bf16, k = quad*4+j), so P feeds PV
//      directly from registers: 32 MFMA16s per chunk (same FLOPs).
// K and V both load to registers via volatile asm (cannot be latency-sunk,
// the R13/R14 killer); K ping-pong prefetched one chunk ahead. Counted
// vmcnt(16) before QK (drains K(c), leaves 16 V), vmcnt(8) before PV
// (drains V, leaves 8 K(c+1)) -- no full drains in the loop. ZERO LDS,
// zero barriers. l-sum is per-lane scalar (q=col), quad-reduced by 2
// shfl_xor in the epilogue. No split-K, no atomics, single plain store.
// 2048 one-wave blocks (LPT order), __launch_bounds__(64,2).

typedef __attribute__((ext_vector_type(8))) __bf16 bf16x8;
typedef __attribute__((ext_vector_type(4))) __bf16 bf16x4;
typedef __attribute__((ext_vector_type(4))) float floatx4;
typedef __attribute__((ext_vector_type(2))) float f32x2;
typedef __attribute__((ext_vector_type(4))) short s16x4;

#define S_LEN 2048
#define NH 16
#define HS 64
#define RS 1024                     // fp32 floats between seq positions
#define KB_ELEMS (2 * NH * S_LEN * HS)   // 4,194,304 bf16 = 8 MB
#define SCALE_LOG2E 0.18033688011112042f // 0.125 / ln(2)

#if __has_builtin(__builtin_amdgcn_exp2f)
#define EXP2(x) __builtin_amdgcn_exp2f(x)
#else
#define EXP2(x) exp2f(x)
#endif

#define MFMA(a, b, c) __builtin_amdgcn_mfma_f32_16x16x32_bf16(a, b, c, 0, 0, 0)
// v_mfma_f32_16x16x16_bf16: A/B = 2 VGPRs (4 bf16 as v4i16), C/D = 4 VGPRs
#define MFMA16(a, b, c) __builtin_amdgcn_mfma_f32_16x16x16bf16_1k(a, b, c, 0, 0, 0)

// ---- pre-pass: K -> bf16 [b,h,s,d] (scaled), V -> bf16 V^T [b,h,d,s] ----
__global__ __launch_bounds__(256) void conv_kv(const float* __restrict__ k,
                                               const float* __restrict__ v,
                                               __bf16* __restrict__ kbuf,
                                               __bf16* __restrict__ vbuf)
{
    __shared__ __align__(16) __bf16 tile[64][72];     // [d][s], 144B rows
    const int tid = threadIdx.x;

    const int bh = blockIdx.x >> 5;                   // 32 s-tiles per (b,h)
    const int st = blockIdx.x & 31;
    const int b = bh >> 4, h = bh & 15;
    const int s0 = st * 64;

#pragma unroll
    for (int it = 0; it < 4; ++it) {
        const int idx = it * 256 + tid;
        const int s = idx >> 4, f4 = idx & 15;
        floatx4 val = *(const floatx4*)(k + ((size_t)(b * 2048 + s0 + s)) * 1024 + h * 64 + f4 * 4);
        bf16x4 w;
        w[0] = (__bf16)(val[0] * SCALE_LOG2E); w[1] = (__bf16)(val[1] * SCALE_LOG2E);
        w[2] = (__bf16)(val[2] * SCALE_LOG2E); w[3] = (__bf16)(val[3] * SCALE_LOG2E);
        *(bf16x4*)(kbuf + ((size_t)((b * 16 + h) * 2048 + s0 + s)) * 64 + f4 * 4) = w;
    }

#pragma unroll
    for (int it = 0; it < 4; ++it) {
        const int idx = it * 256 + tid;
        const int s = idx >> 4, f4 = idx & 15;
        floatx4 val = *(const floatx4*)(v + ((size_t)(b * 2048 + s0 + s)) * 1024 + h * 64 + f4 * 4);
#pragma unroll
        for (int i = 0; i < 4; ++i)
            tile[f4 * 4 + i][s] = (__bf16)val[i];
    }
    __syncthreads();
#pragma unroll
    for (int it = 0; it < 2; ++it) {
        const int idx = it * 256 + tid;
        const int d = idx >> 3, sg = idx & 7;
        bf16x8 w = *(const bf16x8*)&tile[d][sg * 8];
        *(bf16x8*)(vbuf + ((size_t)((b * 16 + h) * 64 + d)) * 2048 + s0 + sg * 8) = w;
    }
}

// ---- main kernel: 1 wave/block, 32 q-rows, all-register K/V/P, no LDS ----
__global__ __launch_bounds__(64, 2) void fa_part14(
    const float* __restrict__ q, const __bf16* __restrict__ kb,
    const __bf16* __restrict__ vt, const int* __restrict__ glm_mask,
    float* __restrict__ out)
{
    const int lane = threadIdx.x;                 // one wave per block
    const int col  = lane & 15, quad = lane >> 4;

    // LPT order: longest q-tiles first (q0 descending), heads fastest
    const int tile = blockIdx.x >> 5;             // 0..63
    const int head = blockIdx.x & 31;
    const int b = head >> 4, h = head & 15;
    const int q0 = (63 - tile) * 32;              // this wave's 32 q-rows

    const int bp = glm_mask[b];
    int klen = q0 + 32; if (bp > klen) klen = bp;
    const int nch = (klen + 63) >> 6;             // 1..32

    const __bf16* kbh = kb + ((size_t)(b * 16 + h)) * (2048 * 64);
    const __bf16* vth = vt + ((size_t)(b * 16 + h)) * (64 * 2048);
    const size_t obase = (size_t)b * (S_LEN * RS) + h * HS;

    // per-lane base addresses
    // K A-frag: lane holds K[k=kg*16+col][d=hf*32+quad*8+j] -> 16B granules
    const char* kcp = (const char*)kbh + (size_t)col * 128 + quad * 16;
    // V B-frag (16x16x16): lane holds V^T[d=f*16+col][k=kg*16+quad*4+j] -> 8B
    const char* vcp = (const char*)vth + (size_t)col * 4096 + quad * 8;

// K(c) -> DST (8 x 16B volatile asm loads; cannot be sunk)
#define LOADK(DST, K0)                                                         \
  _Pragma("unroll")                                                            \
  for (int kg = 0; kg < 4; ++kg)                                               \
    _Pragma("unroll")                                                          \
    for (int hf = 0; hf < 2; ++hf) {                                           \
      unsigned long long ka = (unsigned long long)(kcp +                       \
          (size_t)(K0) * 128 + kg * 2048 + hf * 64);                           \
      __asm__ __volatile__("global_load_dwordx4 %0, %1, off"                   \
                           : "=v"(DST[kg][hf]) : "v"(ka) : "memory");          \
    }

// V(c) -> bv (16 x 8B volatile asm loads)
#define LOADV(K0)                                                              \
  _Pragma("unroll")                                                            \
  for (int f = 0; f < 4; ++f)                                                  \
    _Pragma("unroll")                                                          \
    for (int kg = 0; kg < 4; ++kg) {                                           \
      unsigned long long va = (unsigned long long)(vcp +                       \
          (size_t)(K0) * 2 + f * 65536 + kg * 32);                             \
      __asm__ __volatile__("global_load_dwordx2 %0, %1, off"                   \
                           : "=v"(bv[f][kg]) : "v"(va) : "memory");            \
    }

    // Q B-frags: aq[rg][half], lane holds Q[q=q0+rg*16+col][d=half*32+quad*8+j]
    bf16x8 aq[2][2];
#pragma unroll
    for (int rg = 0; rg < 2; ++rg) {
        const float* qp = q + obase + (size_t)(q0 + rg * 16 + col) * RS + quad * 8;
        floatx4 a0 = *(const floatx4*)qp;
        floatx4 a1 = *(const floatx4*)(qp + 4);
        floatx4 a2 = *(const floatx4*)(qp + 32);
        floatx4 a3 = *(const floatx4*)(qp + 36);
#pragma unroll
        for (int i = 0; i < 4; ++i) {
            aq[rg][0][i] = (__bf16)a0[i]; aq[rg][0][4 + i] = (__bf16)a1[i];
            aq[rg][1][i] = (__bf16)a2[i]; aq[rg][1][4 + i] = (__bf16)a3[i];
        }
    }

    floatx4 o[2][4];                // O C-frags: row = q0+rg*16+quad*4+r, d = f*16+col
    float ls[2] = {0.f, 0.f};       // per-lane l partial for q = q0+rg*16+col
#pragma unroll
    for (int rg = 0; rg < 2; ++rg)
#pragma unroll
        for (int f = 0; f < 4; ++f)
            o[rg][f] = (floatx4){0.f, 0.f, 0.f, 0.f};

    bf16x8 bkA[4][2], bkB[4][2];
    f32x2 bv[4][4];

    LOADK(bkA, 0);                  // prologue: K(0) in flight (8 vm ops)

// One 64-col chunk. BKC = current K frags, BKN = next (ping-pong names).
#define CHUNK(C, BKC, BKN)                                                     \
  {                                                                            \
    const int k0 = (C) * 64;                                                   \
    LOADV(k0);            /* 16 V ops enqueued behind the 8 K(c) ops */        \
    /* drain the 8 oldest (K(c)); 16 V stay in flight */                       \
    __asm__ __volatile__("s_waitcnt vmcnt(16)" ::: "memory");                  \
    __builtin_amdgcn_sched_barrier(0);                                         \
    /* QK^T swapped: S^T = K . Q^T -> lane holds P[q=col][k=..quad*4+r] */     \
    floatx4 z_ = {0.f, 0.f, 0.f, 0.f};                                         \
    floatx4 s[2][4];                                                           \
    __builtin_amdgcn_s_setprio(1);                                             \
    _Pragma("unroll")                                                          \
    for (int rg = 0; rg < 2; ++rg)                                             \
      _Pragma("unroll")                                                        \
      for (int kg = 0; kg < 4; ++kg) {                                         \
        s[rg][kg] = MFMA(BKC[kg][0], aq[rg][0], z_);                           \
        s[rg][kg] = MFMA(BKC[kg][1], aq[rg][1], s[rg][kg]);                    \
      }                                                                        \
    __builtin_amdgcn_s_setprio(0);                                             \
    /* prefetch K(c+1) (volatile: stays here, in flight through PV) */         \
    if ((C) + 1 < nch) { LOADK(BKN, k0 + 64); }                                \
    /* exp + mask + pack to A-frags of 16x16x16 (all in registers) */          \
    const bool full = (k0 + 63 < bp) || (k0 + 63 <= q0);                       \
    s16x4 pa[2][4];                                                            \
    _Pragma("unroll")                                                          \
    for (int rg = 0; rg < 2; ++rg) {                                           \
      const int qi = q0 + rg * 16 + col;                                       \
      _Pragma("unroll")                                                        \
      for (int kg = 0; kg < 4; ++kg) {                                         \
        bf16x4 pv4;                                                            \
        _Pragma("unroll")                                                      \
        for (int r = 0; r < 4; ++r) {                                          \
          float e = EXP2(s[rg][kg][r]);                                        \
          if (!full) {                                                         \
            const int kj = k0 + kg * 16 + quad * 4 + r;                        \
            if (!((kj < bp) || (kj <= qi))) e = 0.f;                           \
          }                                                                    \
          ls[rg] += e;                                                         \
          pv4[r] = (__bf16)e;                                                  \
        }                                                                      \
        pa[rg][kg] = __builtin_bit_cast(s16x4, pv4);                           \
      }                                                                        \
    }                                                                          \
    /* drain V(c); K(c+1) stays in flight (counted) */                         \
    if ((C) + 1 < nch) {                                                       \
      __asm__ __volatile__("s_waitcnt vmcnt(8)" ::: "memory");                 \
    } else {                                                                   \
      __asm__ __volatile__("s_waitcnt vmcnt(0)" ::: "memory");                 \
    }                                                                          \
    __builtin_amdgcn_sched_barrier(0);  /* rule #18: PV stays behind wait */   \
    /* PV: 32 x mfma 16x16x16, P direct from registers */                      \
    __builtin_amdgcn_s_setprio(1);                                             \
    _Pragma("unroll")                                                          \
    for (int rg = 0; rg < 2; ++rg)                                             \
      _Pragma("unroll")                                                        \
      for (int f = 0; f < 4; ++f)                                              \
        _Pragma("unroll")                                                      \
        for (int kg = 0; kg < 4; ++kg)                                         \
          o[rg][f] = MFMA16(pa[rg][kg],                                        \
                            __builtin_bit_cast(s16x4, bv[f][kg]), o[rg][f]);   \
    __builtin_amdgcn_s_setprio(0);                                             \
  }

    int c = 0;
    for (; c + 1 < nch; c += 2) {
        CHUNK(c,     bkA, bkB);
        CHUNK(c + 1, bkB, bkA);
    }
    if (c < nch)
        CHUNK(c, bkA, bkB);

    // epilogue: l lives per-lane at q=col; reduce across quads, then
    // redistribute to the C-frag rows (q = quad*4+r) via shfl.
#pragma unroll
    for (int rg = 0; rg < 2; ++rg) {
        float l = ls[rg];
        l += __shfl_xor(l, 16);
        l += __shfl_xor(l, 32);                   // all quads summed, q=rg*16+col
        const float linv = (l > 0.f) ? (1.f / l) : 0.f;
#pragma unroll
        for (int r = 0; r < 4; ++r) {
            const float inv = __shfl(linv, quad * 4 + r);   // lane col=quad*4+r
            const int row = q0 + rg * 16 + quad * 4 + r;
            float* op = out + obase + (size_t)row * RS;
#pragma unroll
            for (int f = 0; f < 4; ++f)
                op[f * 16 + col] = o[rg][f][r] * inv;
        }
    }
}

extern "C" void kernel_launch(void* const* d_in, const int* in_sizes, int n_in,
                              void* d_out, int out_size, void* d_ws, size_t ws_size,
                              hipStream_t stream) {
    const float* q = (const float*)d_in[0];
    const float* k = (const float*)d_in[1];
    const float* v = (const float*)d_in[2];
    const int* glm = (const int*)d_in[3];
    float* out     = (float*)d_out;

    const size_t kb_bytes = (size_t)KB_ELEMS * 2;            // 8 MB
    __bf16* kbuf = (__bf16*)d_ws;
    __bf16* vbuf = (__bf16*)((char*)d_ws + kb_bytes);

    hipLaunchKernelGGL(conv_kv, dim3(1024), dim3(256), 0, stream,
                       k, v, kbuf, vbuf);
    // 64 q-tiles (LPT order) x 32 heads = 2048 one-wave blocks (8/CU)
    hipLaunchKernelGGL(fa_part14, dim3(2048), dim3(64), 0, stream,
                       q, kbuf, vbuf, glm, out);
}

// Round 13
// 143.764 us; speedup vs baseline: 1.6470x; 1.6470x over previous
//
#include <hip/hip_runtime.h>
#include <hip/hip_bf16.h>

// GLM flash attention fwd: b=2, s=2048, nh=16, hs=64, fp32 I/O, bf16 MFMA.
// R20: fragment-tiled K/V staging -> every fa load is ONE contiguous segment.
// Cross-round invariant found: per-chunk wall ~= 6.3 cyc per discontiguous
// 32-64B memory segment (R17: 192 seg -> 2.4K cyc; R19: 384 seg -> 4.8K cyc)
// -- the kernel is L2-REQUEST-RATE bound, not byte- or latency-bound.
// Fix: conv_kv (which already rewrites K/V) emits MFMA-fragment-ordered
// tiles: kbuf tile (kb,hf) = 1KB, slot l = K[kb*16+(l&15)][hf*32+(l>>4)*8+j]
// (A-frag of swapped QK, scale folded); vbuf tile (kb,f) = 512B, slot l =
// V[kb*16+(l>>4)*4+j][f*16+(l&15)] (B-frag of 16x16x16 PV). fa loads become
// base + lane*16 / lane*8: 8 K + 16 V = 24 segments/chunk (16x fewer).
// fa compute core byte-identical to R19 (passed): swapped QK^T -> P in
// registers in MFMA16 A-layout -> PV direct, zero LDS, zero barriers,
// counted vmcnt(16)/vmcnt(8), volatile-asm loads (unsinkable), no split-K,
// no atomics, in-register normalize. 2048 one-wave blocks, LPT order.

typedef __attribute__((ext_vector_type(8))) __bf16 bf16x8;
typedef __attribute__((ext_vector_type(4))) __bf16 bf16x4;
typedef __attribute__((ext_vector_type(4))) float floatx4;
typedef __attribute__((ext_vector_type(2))) float f32x2;
typedef __attribute__((ext_vector_type(4))) short s16x4;

#define S_LEN 2048
#define NH 16
#define HS 64
#define RS 1024                     // fp32 floats between seq positions
#define KB_ELEMS (2 * NH * S_LEN * HS)   // 4,194,304 bf16 = 8 MB
#define BH_ELEMS (S_LEN * HS)            // 131072 bf16 per (b,h)
#define SCALE_LOG2E 0.18033688011112042f // 0.125 / ln(2)

#if __has_builtin(__builtin_amdgcn_exp2f)
#define EXP2(x) __builtin_amdgcn_exp2f(x)
#else
#define EXP2(x) exp2f(x)
#endif

#define MFMA(a, b, c) __builtin_amdgcn_mfma_f32_16x16x32_bf16(a, b, c, 0, 0, 0)
// v_mfma_f32_16x16x16_bf16: A/B = 2 VGPRs (4 bf16 as v4i16), C/D = 4 VGPRs
#define MFMA16(a, b, c) __builtin_amdgcn_mfma_f32_16x16x16bf16_1k(a, b, c, 0, 0, 0)

// ---- pre-pass: K -> A-frag tiles (scaled), V -> MFMA16-B-frag tiles ----
// kbuf, per (b,h): tile (kb in [0,128), hf in [0,2)) of 1KB at offset
//   ((kb*2+hf)*512 + l*8) elems; slot l (= quad*16+col) holds 8 bf16:
//   K[kb*16+col][hf*32+quad*8+j] * SCALE_LOG2E.
// vbuf, per (b,h): tile (kb, f in [0,4)) of 512B at offset
//   ((kb*4+f)*256 + l*4) elems; slot l holds 4 bf16:
//   V[kb*16+(l>>4)*4+j][f*16+(l&15)].
__global__ __launch_bounds__(256) void conv_kv(const float* __restrict__ k,
                                               const float* __restrict__ v,
                                               __bf16* __restrict__ kbuf,
                                               __bf16* __restrict__ vbuf)
{
    __shared__ __align__(16) __bf16 tile[64][72];     // [d][s], 144B rows
    const int tid = threadIdx.x;

    const int bh = blockIdx.x >> 5;                   // 32 s-tiles per (b,h)
    const int st = blockIdx.x & 31;
    const int b = bh >> 4, h = bh & 15;
    const int s0 = st * 64;
    const int kb0 = st * 4;                           // base 16-k block

    __bf16* kout = kbuf + (size_t)(b * 16 + h) * BH_ELEMS;
    __bf16* vout = vbuf + (size_t)(b * 16 + h) * BH_ELEMS;

    // K: read coalesced (32B/thread along rows), write A-frag slots
#pragma unroll
    for (int it = 0; it < 2; ++it) {
        const int idx = it * 256 + tid;               // 0..511
        const int sl = idx >> 3;                      // local k row 0..63
        const int g  = idx & 7;                       // 8-float d-granule
        const float* kp = k + ((size_t)(b * 2048 + s0 + sl)) * 1024 + h * 64 + g * 8;
        floatx4 v0 = *(const floatx4*)kp;
        floatx4 v1 = *(const floatx4*)(kp + 4);
        bf16x8 w;
#pragma unroll
        for (int i = 0; i < 4; ++i) {
            w[i]     = (__bf16)(v0[i] * SCALE_LOG2E);
            w[4 + i] = (__bf16)(v1[i] * SCALE_LOG2E);
        }
        const int kb = kb0 + (sl >> 4);
        const int l  = (g & 3) * 16 + (sl & 15);      // quad=g&3, col=sl&15
        *(bf16x8*)(kout + ((kb * 2 + (g >> 2)) * 512 + l * 8)) = w;
    }

    // V: build [d][s] transpose in LDS (as before)
#pragma unroll
    for (int it = 0; it < 4; ++it) {
        const int idx = it * 256 + tid;
        const int s = idx >> 4, f4 = idx & 15;
        floatx4 val = *(const floatx4*)(v + ((size_t)(b * 2048 + s0 + s)) * 1024 + h * 64 + f4 * 4);
#pragma unroll
        for (int i = 0; i < 4; ++i)
            tile[f4 * 4 + i][s] = (__bf16)val[i];
    }
    __syncthreads();

    // emit B-frag slots (8B/thread, writes fully coalesced per tile)
#pragma unroll
    for (int it = 0; it < 4; ++it) {
        const int idx = it * 256 + tid;               // 0..1023
        const int kbl = idx >> 8;                     // 0..3
        const int f   = (idx >> 6) & 3;
        const int l   = idx & 63;
        const int col = l & 15, q4 = l >> 4;
        bf16x4 w = *(const bf16x4*)&tile[f * 16 + col][kbl * 16 + q4 * 4];
        *(bf16x4*)(vout + (((kb0 + kbl) * 4 + f) * 256 + l * 4)) = w;
    }
}

// ---- main kernel: 1 wave/block, 32 q-rows, all-register, 24 segments/chunk ----
__global__ __launch_bounds__(64, 2) void fa_part15(
    const float* __restrict__ q, const __bf16* __restrict__ kb,
    const __bf16* __restrict__ vt, const int* __restrict__ glm_mask,
    float* __restrict__ out)
{
    const int lane = threadIdx.x;                 // one wave per block
    const int col  = lane & 15, quad = lane >> 4;

    // LPT order: longest q-tiles first (q0 descending), heads fastest
    const int tile = blockIdx.x >> 5;             // 0..63
    const int head = blockIdx.x & 31;
    const int b = head >> 4, h = head & 15;
    const int q0 = (63 - tile) * 32;              // this wave's 32 q-rows

    const int bp = glm_mask[b];
    int klen = q0 + 32; if (bp > klen) klen = bp;
    const int nch = (klen + 63) >> 6;             // 1..32

    const __bf16* kbh = kb + (size_t)(b * 16 + h) * BH_ELEMS;
    const __bf16* vth = vt + (size_t)(b * 16 + h) * BH_ELEMS;
    const size_t obase = (size_t)b * (S_LEN * RS) + h * HS;

    // per-lane slot bases (fully coalesced: lane-linear)
    const char* klp = (const char*)kbh + lane * 16;
    const char* vlp = (const char*)vth + lane * 8;

// K(c) -> DST (8 x 16B volatile asm loads, each ONE 1KB segment)
#define LOADK(DST, K0)                                                         \
  _Pragma("unroll")                                                            \
  for (int kg = 0; kg < 4; ++kg)                                               \
    _Pragma("unroll")                                                          \
    for (int hf = 0; hf < 2; ++hf) {                                           \
      unsigned long long ka = (unsigned long long)(klp +                       \
          (size_t)(K0) * 128 + kg * 2048 + hf * 1024);                         \
      __asm__ __volatile__("global_load_dwordx4 %0, %1, off"                   \
                           : "=v"(DST[kg][hf]) : "v"(ka) : "memory");          \
    }

// V(c) -> bv (16 x 8B volatile asm loads, each ONE 512B segment)
#define LOADV(K0)                                                              \
  _Pragma("unroll")                                                            \
  for (int kg = 0; kg < 4; ++kg)                                               \
    _Pragma("unroll")                                                          \
    for (int f = 0; f < 4; ++f) {                                              \
      unsigned long long va = (unsigned long long)(vlp +                       \
          (size_t)(K0) * 128 + kg * 2048 + f * 512);                           \
      __asm__ __volatile__("global_load_dwordx2 %0, %1, off"                   \
                           : "=v"(bv[f][kg]) : "v"(va) : "memory");            \
    }

    // Q B-frags: aq[rg][half], lane holds Q[q=q0+rg*16+col][d=half*32+quad*8+j]
    bf16x8 aq[2][2];
#pragma unroll
    for (int rg = 0; rg < 2; ++rg) {
        const float* qp = q + obase + (size_t)(q0 + rg * 16 + col) * RS + quad * 8;
        floatx4 a0 = *(const floatx4*)qp;
        floatx4 a1 = *(const floatx4*)(qp + 4);
        floatx4 a2 = *(const floatx4*)(qp + 32);
        floatx4 a3 = *(const floatx4*)(qp + 36);
#pragma unroll
        for (int i = 0; i < 4; ++i) {
            aq[rg][0][i] = (__bf16)a0[i]; aq[rg][0][4 + i] = (__bf16)a1[i];
            aq[rg][1][i] = (__bf16)a2[i]; aq[rg][1][4 + i] = (__bf16)a3[i];
        }
    }

    floatx4 o[2][4];                // O C-frags: row = q0+rg*16+quad*4+r, d = f*16+col
    float ls[2] = {0.f, 0.f};       // per-lane l partial for q = q0+rg*16+col
#pragma unroll
    for (int rg = 0; rg < 2; ++rg)
#pragma unroll
        for (int f = 0; f < 4; ++f)
            o[rg][f] = (floatx4){0.f, 0.f, 0.f, 0.f};

    bf16x8 bkA[4][2], bkB[4][2];
    f32x2 bv[4][4];

    LOADK(bkA, 0);                  // prologue: K(0) in flight (8 vm ops)

// One 64-col chunk. BKC = current K frags, BKN = next (ping-pong names).
#define CHUNK(C, BKC, BKN)                                                     \
  {                                                                            \
    const int k0 = (C) * 64;                                                   \
    LOADV(k0);            /* 16 V ops enqueued behind the 8 K(c) ops */        \
    /* drain the 8 oldest (K(c)); 16 V stay in flight */                       \
    __asm__ __volatile__("s_waitcnt vmcnt(16)" ::: "memory");                  \
    __builtin_amdgcn_sched_barrier(0);                                         \
    /* QK^T swapped: S^T = K . Q^T -> lane holds P[q=col][k=..quad*4+r] */     \
    floatx4 z_ = {0.f, 0.f, 0.f, 0.f};                                         \
    floatx4 s[2][4];                                                           \
    __builtin_amdgcn_s_setprio(1);                                             \
    _Pragma("unroll")                                                          \
    for (int rg = 0; rg < 2; ++rg)                                             \
      _Pragma("unroll")                                                        \
      for (int kg = 0; kg < 4; ++kg) {                                         \
        s[rg][kg] = MFMA(BKC[kg][0], aq[rg][0], z_);                           \
        s[rg][kg] = MFMA(BKC[kg][1], aq[rg][1], s[rg][kg]);                    \
      }                                                                        \
    __builtin_amdgcn_s_setprio(0);                                             \
    /* prefetch K(c+1) (volatile: stays here, in flight through PV) */         \
    if ((C) + 1 < nch) { LOADK(BKN, k0 + 64); }                                \
    /* exp + mask + pack to A-frags of 16x16x16 (all in registers) */          \
    const bool full = (k0 + 63 < bp) || (k0 + 63 <= q0);                       \
    s16x4 pa[2][4];                                                            \
    _Pragma("unroll")                                                          \
    for (int rg = 0; rg < 2; ++rg) {                                           \
      const int qi = q0 + rg * 16 + col;                                       \
      _Pragma("unroll")                                                        \
      for (int kg = 0; kg < 4; ++kg) {                                         \
        bf16x4 pv4;                                                            \
        _Pragma("unroll")                                                      \
        for (int r = 0; r < 4; ++r) {                                          \
          float e = EXP2(s[rg][kg][r]);                                        \
          if (!full) {                                                         \
            const int kj = k0 + kg * 16 + quad * 4 + r;                        \
            if (!((kj < bp) || (kj <= qi))) e = 0.f;                           \
          }                                                                    \
          ls[rg] += e;                                                         \
          pv4[r] = (__bf16)e;                                                  \
        }                                                                      \
        pa[rg][kg] = __builtin_bit_cast(s16x4, pv4);                           \
      }                                                                        \
    }                                                                          \
    /* drain V(c); K(c+1) stays in flight (counted) */                         \
    if ((C) + 1 < nch) {                                                       \
      __asm__ __volatile__("s_waitcnt vmcnt(8)" ::: "memory");                 \
    } else {                                                                   \
      __asm__ __volatile__("s_waitcnt vmcnt(0)" ::: "memory");                 \
    }                                                                          \
    __builtin_amdgcn_sched_barrier(0);  /* rule #18: PV stays behind wait */   \
    /* PV: 32 x mfma 16x16x16, P direct from registers */                      \
    __builtin_amdgcn_s_setprio(1);                                             \
    _Pragma("unroll")                                                          \
    for (int rg = 0; rg < 2; ++rg)                                             \
      _Pragma("unroll")                                                        \
      for (int f = 0; f < 4; ++f)                                              \
        _Pragma("unroll")                                                      \
        for (int kg = 0; kg < 4; ++kg)                                         \
          o[rg][f] = MFMA16(pa[rg][kg],                                        \
                            __builtin_bit_cast(s16x4, bv[f][kg]), o[rg][f]);   \
    __builtin_amdgcn_s_setprio(0);                                             \
  }

    int c = 0;
    for (; c + 1 < nch; c += 2) {
        CHUNK(c,     bkA, bkB);
        CHUNK(c + 1, bkB, bkA);
    }
    if (c < nch)
        CHUNK(c, bkA, bkB);

    // epilogue: l lives per-lane at q=col; reduce across quads, then
    // redistribute to the C-frag rows (q = quad*4+r) via shfl.
#pragma unroll
    for (int rg = 0; rg < 2; ++rg) {
        float l = ls[rg];
        l += __shfl_xor(l, 16);
        l += __shfl_xor(l, 32);                   // all quads summed, q=rg*16+col
        const float linv = (l > 0.f) ? (1.f / l) : 0.f;
#pragma unroll
        for (int r = 0; r < 4; ++r) {
            const float inv = __shfl(linv, quad * 4 + r);   // lane col=quad*4+r
            const int row = q0 + rg * 16 + quad * 4 + r;
            float* op = out + obase + (size_t)row * RS;
#pragma unroll
            for (int f = 0; f < 4; ++f)
                op[f * 16 + col] = o[rg][f][r] * inv;
        }
    }
}

extern "C" void kernel_launch(void* const* d_in, const int* in_sizes, int n_in,
                              void* d_out, int out_size, void* d_ws, size_t ws_size,
                              hipStream_t stream) {
    const float* q = (const float*)d_in[0];
    const float* k = (const float*)d_in[1];
    const float* v = (const float*)d_in[2];
    const int* glm = (const int*)d_in[3];
    float* out     = (float*)d_out;

    const size_t kb_bytes = (size_t)KB_ELEMS * 2;            // 8 MB
    __bf16* kbuf = (__bf16*)d_ws;
    __bf16* vbuf = (__bf16*)((char*)d_ws + kb_bytes);

    hipLaunchKernelGGL(conv_kv, dim3(1024), dim3(256), 0, stream,
                       k, v, kbuf, vbuf);
    // 64 q-tiles (LPT order) x 32 heads = 2048 one-wave blocks (8/CU)
    hipLaunchKernelGGL(fa_part15, dim3(2048), dim3(64), 0, stream,
                       q, kbuf, vbuf, glm, out);
}